// Round 9
// baseline (239.179 us; speedup 1.0000x reference)
//
#include <hip/hip_runtime.h>
#include <math.h>

// Problem constants (fixed by the reference).
#define BB    1024
#define SS    277
#define RR    76
#define ZZ    56
#define NLHS  24
#define NROWS (BB*SS)                    // 283648
#define ROWS_PER_BLOCK 64                // one wave per block
#define NBCE (NROWS/ROWS_PER_BLOCK)      // 4432 (exact)
#define NMOM ZZ                          // 56 (placed FIRST in the grid)
#define NBLK (NBCE + NMOM)               // 4488
#define V4_PER_BLOCK (ROWS_PER_BLOCK*RR/4) // 1216
#define BLK_ELEMS (ROWS_PER_BLOCK*RR)    // 4864
#define TOTAL_ELEMS 21558272.0           // B*S*R

static_assert(NROWS % ROWS_PER_BLOCK == 0, "rows divide blocks");

#define LN2F  0.69314718056f
#define NLN2F (-144.26950409f)   /* -100 / ln2 */

// blocks [0, NMOM): moment kernel, one column j per block (launched first so the
//   long-ish serial mu loop hides under the 4432 bce blocks).
// blocks [NMOM, NBLK): masked-softmax BCE, one wave = 64 rows, one thread = one
//   row held in registers (R3-proven math, absmax 0). Small blocks maximize
//   schedulable units per CU (~16 wg/CU vs 4.3 at 256-thread blocks) to raise
//   wave concurrency — the R3 counter evidence says we are latency-bound with
//   a grid-starved occupancy of 34.6%.
__global__ __launch_bounds__(64, 4) void fused_kernel(
    const float* __restrict__ model,
    const float* __restrict__ target,
    const float* __restrict__ masks,
    const int*   __restrict__ ind_to_lhs,
    const float* __restrict__ mu,
    double* __restrict__ partials)
{
    __shared__ unsigned int  smb[NLHS*4];       // 96-bit mask per lhs, padded
    __shared__ int           sm_lhs[RR];
    __shared__ unsigned char sm_idx[ROWS_PER_BLOCK];

    const int tid = threadIdx.x;   // == lane (single wave)

    if (blockIdx.x < NMOM) {
        // ---------------- mom path: var[:,j] for j = blockIdx ----------------
        const int j = blockIdx.x;
        const int i = (tid < ZZ) ? tid : 0;
        float dot = 0.f, s1 = 0.f;
        #pragma unroll 8
        for (int b = 0; b < BB; ++b) {
            const float c = mu[b*ZZ + j];     // wave-uniform broadcast
            const float a = mu[b*ZZ + i];     // coalesced across lanes
            dot = fmaf(a, c, dot);
            s1 += c;
        }
        float term = 0.f;
        if (tid < ZZ) {
            const float var = dot * (1.f/BB);
            const float ve  = var - ((tid == j) ? 1.f : 0.f);
            term = tanhf(ve) * ve * (1.f/(ZZ*ZZ));
            if (tid == j) {
                const float am = s1 * (1.f/BB);
                term = fmaf(am*am, 1.f/ZZ, term);
            }
        }
        #pragma unroll
        for (int off = 32; off; off >>= 1) term += __shfl_xor(term, off, 64);
        if (tid == 0) partials[blockIdx.x] = (double)term;
        return;
    }

    // ---------------- bce path ----------------
    const int bce_blk = blockIdx.x - NMOM;

    if (tid < NLHS*4) smb[tid] = 0u;
    if (tid < NLHS*4 - 64) smb[64 + tid] = 0u;
    sm_idx[tid] = 0;
    __syncthreads();

    // Pack masks into bitmasks (parallel, LDS atomicOr).
    for (int e = tid; e < NLHS*RR; e += 64) {
        const int lhs = e / RR;
        const int r   = e - lhs*RR;
        if (masks[e] > 0.5f)
            atomicOr(&smb[lhs*4 + (r >> 5)], 1u << (r & 31));
    }
    for (int i = tid; i < RR; i += 64) sm_lhs[i] = ind_to_lhs[i];

    const size_t blk_base = (size_t)bce_blk * BLK_ELEMS;

    // Coalesced one-hot scan. A float4 never straddles rows (76 = 19 f4).
    // One-hot => at most one hit per float4, exactly one writer per row.
    // WRITE AT EACH HIT (a thread can hit in multiple rows across its 19 f4s).
    {
        const float4* t4 = (const float4*)(target + blk_base);
        #pragma unroll
        for (int k = 0; k < 19; ++k) {
            const int v4 = tid + 64*k;
            const float4 t = t4[v4];
            int he = -1;
            const int e = v4*4;
            if (t.x > 0.5f) he = e;
            if (t.y > 0.5f) he = e+1;
            if (t.z > 0.5f) he = e+2;
            if (t.w > 0.5f) he = e+3;
            if (he >= 0) {
                const int row = he / RR;
                sm_idx[row] = (unsigned char)(he - row*RR);
            }
        }
    }
    __syncthreads();

    // --- per-row compute, all from registers (R3-proven) ---
    const int true_r = (int)sm_idx[tid];
    const int lhs    = sm_lhs[true_r];
    const unsigned int mw0 = smb[lhs*4 + 0];
    const unsigned int mw1 = smb[lhs*4 + 1];
    const unsigned int mw2 = smb[lhs*4 + 2];

    const float4* m4 = (const float4*)(model + blk_base + (size_t)tid * RR);
    float4 x[19];
    #pragma unroll
    for (int k = 0; k < 19; ++k) x[k] = m4[k];   // 19 independent loads

    // Pass A: apply mask (-1e30 for masked), row max.
    float mx = -1e30f;
    #pragma unroll
    for (int k = 0; k < 19; ++k) {
        #pragma unroll
        for (int c = 0; c < 4; ++c) {
            const int r = k*4 + c;
            const unsigned int mw = (r < 32) ? mw0 : ((r < 64) ? mw1 : mw2);
            float* xp = (&x[k].x) + c;
            const bool un = (mw >> (r & 31)) & 1u;
            const float xm = un ? *xp : -1e30f;
            *xp = xm;
            mx = fmaxf(mx, xm);
        }
    }

    // Pass B: e_r = exp(x_r - mx) (masked -> 0), sum.
    float s = 0.f;
    #pragma unroll
    for (int k = 0; k < 19; ++k) {
        #pragma unroll
        for (int c = 0; c < 4; ++c) {
            float* xp = (&x[k].x) + c;
            const float e = __expf(*xp - mx);
            *xp = e;
            s += e;
        }
    }

    // Pass C: clamped log(1-p) over ALL r (log2-domain, ln2 factored out),
    // plus p at the target index.
    const float inv = 1.f / s;
    float sum_l2 = 0.f;
    float p_true = 0.f;
    #pragma unroll
    for (int k = 0; k < 19; ++k) {
        #pragma unroll
        for (int c = 0; c < 4; ++c) {
            const int r = k*4 + c;
            const float p  = (&x[k].x)[c] * inv;
            const float l2 = __log2f(1.f - p);
            sum_l2 += fmaxf(l2, NLN2F);
            if (r == true_r) p_true = p;
        }
    }
    float row_sum = LN2F * sum_l2;
    // Swap the true_r element's non-target term for the target term.
    const float l1c_t = fmaxf(LN2F * __log2f(1.f - p_true), -100.f);
    const float lp_t  = fmaxf(__logf(p_true), -100.f);   // p_true==0 (masked) -> -100
    row_sum += lp_t - l1c_t;

    // Single-wave butterfly -> one double partial per block (no atomics).
    #pragma unroll
    for (int off = 32; off; off >>= 1) row_sum += __shfl_xor(row_sum, off, 64);
    if (tid == 0) partials[blockIdx.x] = (double)row_sum;
}

// Sum NBCE bce partials + NMOM mom partials with the right scales.
__global__ __launch_bounds__(256) void final_kernel(
    const double* __restrict__ partials, float* __restrict__ out)
{
    __shared__ double sred[4];
    const int tid = threadIdx.x;
    double s = 0.0;
    for (int k = NMOM + tid; k < NBLK; k += 256) s += partials[k];
    double m = (tid < NMOM) ? partials[tid] : 0.0;
    double val = s * (-(double)SS / TOTAL_ELEMS) + m;
    #pragma unroll
    for (int off = 32; off; off >>= 1) val += __shfl_xor(val, off, 64);
    if ((tid & 63) == 0) sred[tid >> 6] = val;
    __syncthreads();
    if (tid == 0) out[0] = (float)((sred[0] + sred[1]) + (sred[2] + sred[3]));
}

extern "C" void kernel_launch(void* const* d_in, const int* in_sizes, int n_in,
                              void* d_out, int out_size, void* d_ws, size_t ws_size,
                              hipStream_t stream) {
    const float* model  = (const float*)d_in[0];   // [B,S,R]
    const float* mu     = (const float*)d_in[1];   // [B,Z]
    // d_in[2] = log_var — unused by the reference output
    const float* target = (const float*)d_in[3];   // [B,S,R] one-hot
    const float* masks  = (const float*)d_in[4];   // [NLHS,R]
    const int*   ind    = (const int*)  d_in[5];   // [R]
    float* out  = (float*)d_out;
    double* acc = (double*)d_ws;   // [0..NMOM) mom partials, [NMOM..NBLK) bce partials

    fused_kernel<<<NBLK, ROWS_PER_BLOCK, 0, stream>>>(model, target, masks, ind, mu, acc);
    final_kernel<<<1, 256, 0, stream>>>(acc, out);
}

// Round 10
// 215.598 us; speedup vs baseline: 1.1094x; 1.1094x over previous
//
#include <hip/hip_runtime.h>
#include <math.h>

// Problem constants (fixed by the reference).
#define BB    1024
#define SS    277
#define RR    76
#define ZZ    56
#define NLHS  24
#define NROWS (BB*SS)                      // 283648
#define ROWS_PER_BLOCK 256
#define NBCE (NROWS/ROWS_PER_BLOCK)        // 1108 (exact)
#define NMOM ZZ                            // 56 (placed FIRST in the grid)
#define NBLK (NBCE + NMOM)                 // 1164
#define V4_PER_BLOCK (ROWS_PER_BLOCK*RR/4) // 4864
#define BLK_ELEMS (ROWS_PER_BLOCK*RR)      // 19456
#define TOTAL_ELEMS 21558272.0             // B*S*R

static_assert(NROWS % ROWS_PER_BLOCK == 0, "rows divide blocks");

#define LN2F  0.69314718056f
#define NLN2F (-144.26950409f)   /* -100 / ln2 */

// Opaque register pin: the value becomes an asm output, so the compiler
// cannot rematerialize it via a global reload in later passes.
__device__ __forceinline__ float keep(float v) {
    asm volatile("" : "+v"(v));
    return v;
}

// blocks [0, NMOM): moment kernel, one column j per block (runs under bce).
// blocks [NMOM, NBLK): masked-softmax BCE — R3-proven math (absmax 0), one
//   thread = one row of 76 logits HELD IN REGISTERS. launch_bounds(256,4)
//   grants a 128-VGPR budget so x[19] (76 regs) actually stays resident;
//   keep() forbids reload-rematerialization. Evidence: R3 ran at VGPR=44,
//   meaning model was re-read 2-3x from global — the ~75us was line-rate
//   on ~260MB, not on the irreducible 172MB.
__global__ __launch_bounds__(256, 4) void fused_kernel(
    const float* __restrict__ model,
    const float* __restrict__ target,
    const float* __restrict__ masks,
    const int*   __restrict__ ind_to_lhs,
    const float* __restrict__ mu,
    double* __restrict__ partials)
{
    __shared__ unsigned int  smb[NLHS*4];       // 96-bit mask per lhs, padded
    __shared__ int           sm_lhs[RR];
    __shared__ unsigned char sm_idx[ROWS_PER_BLOCK];
    __shared__ float         sm_red[4];
    __shared__ float         sdot[4][64];       // mom path
    __shared__ float         ssum[4];

    const int tid = threadIdx.x;

    if (blockIdx.x < NMOM) {
        // ---------------- mom path: var[:,j] for j = blockIdx ----------------
        const int j    = blockIdx.x;
        const int w    = tid >> 6;
        const int lane = tid & 63;
        const int i    = (lane < ZZ) ? lane : 0;
        float dot = 0.f, s1 = 0.f;
        const int b0 = 256*w;
        #pragma unroll 4
        for (int b = b0; b < b0 + 256; ++b) {
            const float c = mu[b*ZZ + j];     // wave-uniform broadcast
            const float a = mu[b*ZZ + i];     // coalesced across lanes
            dot = fmaf(a, c, dot);
            s1 += c;
        }
        sdot[w][lane] = dot;
        if (lane == 0) ssum[w] = s1;
        __syncthreads();
        if (w == 0) {
            float term = 0.f;
            if (lane < ZZ) {
                const float var = (sdot[0][lane]+sdot[1][lane]+sdot[2][lane]+sdot[3][lane]) * (1.f/BB);
                const float ve  = var - ((lane == j) ? 1.f : 0.f);
                term = tanhf(ve) * ve * (1.f/(ZZ*ZZ));
                if (lane == j) {
                    const float am = (ssum[0]+ssum[1]+ssum[2]+ssum[3]) * (1.f/BB);
                    term = fmaf(am*am, 1.f/ZZ, term);
                }
            }
            #pragma unroll
            for (int off = 32; off; off >>= 1) term += __shfl_xor(term, off, 64);
            if (lane == 0) partials[blockIdx.x] = (double)term;
        }
        return;
    }

    // ---------------- bce path ----------------
    const int bce_blk = blockIdx.x - NMOM;

    if (tid < NLHS*4) smb[tid] = 0u;
    sm_idx[tid] = 0;
    __syncthreads();

    // Pack masks into bitmasks (parallel, LDS atomicOr).
    for (int e = tid; e < NLHS*RR; e += 256) {
        const int lhs = e / RR;
        const int r   = e - lhs*RR;
        if (masks[e] > 0.5f)
            atomicOr(&smb[lhs*4 + (r >> 5)], 1u << (r & 31));
    }
    if (tid < RR) sm_lhs[tid] = ind_to_lhs[tid];

    const size_t blk_base = (size_t)bce_blk * BLK_ELEMS;

    // Issue ALL model loads first (19 independent dwordx4 into registers) so
    // they overlap the target-scan loads in one latency window.
    const float4* m4 = (const float4*)(model + blk_base + (size_t)tid * RR);
    float4 x[19];
    #pragma unroll
    for (int k = 0; k < 19; ++k) x[k] = m4[k];

    // Coalesced one-hot scan. A float4 never straddles rows (76 = 19 f4).
    // One-hot => exactly one writer per row; WRITE AT EACH HIT.
    {
        const float4* t4 = (const float4*)(target + blk_base);
        #pragma unroll
        for (int k = 0; k < 19; ++k) {
            const int v4 = tid + 256*k;
            const float4 t = t4[v4];
            int he = -1;
            const int e = v4*4;
            if (t.x > 0.5f) he = e;
            if (t.y > 0.5f) he = e+1;
            if (t.z > 0.5f) he = e+2;
            if (t.w > 0.5f) he = e+3;
            if (he >= 0) {
                const int row = he / RR;
                sm_idx[row] = (unsigned char)(he - row*RR);
            }
        }
    }
    __syncthreads();

    // Pin every model value into a VGPR (no-op asm; blocks reload-remat).
    #pragma unroll
    for (int k = 0; k < 19; ++k) {
        x[k].x = keep(x[k].x); x[k].y = keep(x[k].y);
        x[k].z = keep(x[k].z); x[k].w = keep(x[k].w);
    }

    // --- per-row compute, all from registers (R3-proven math) ---
    const int true_r = (int)sm_idx[tid];
    const int lhs    = sm_lhs[true_r];
    const unsigned int mw0 = smb[lhs*4 + 0];
    const unsigned int mw1 = smb[lhs*4 + 1];
    const unsigned int mw2 = smb[lhs*4 + 2];

    // Pass A: apply mask (-1e30 for masked), row max.
    float mx = -1e30f;
    #pragma unroll
    for (int k = 0; k < 19; ++k) {
        #pragma unroll
        for (int c = 0; c < 4; ++c) {
            const int r = k*4 + c;
            const unsigned int mw = (r < 32) ? mw0 : ((r < 64) ? mw1 : mw2);
            float* xp = (&x[k].x) + c;
            const bool un = (mw >> (r & 31)) & 1u;
            const float xm = un ? *xp : -1e30f;
            *xp = xm;
            mx = fmaxf(mx, xm);
        }
    }

    // Pass B: e_r = exp(x_r - mx) (masked -> 0), sum.
    float s = 0.f;
    #pragma unroll
    for (int k = 0; k < 19; ++k) {
        #pragma unroll
        for (int c = 0; c < 4; ++c) {
            float* xp = (&x[k].x) + c;
            const float e = __expf(*xp - mx);
            *xp = e;
            s += e;
        }
    }

    // Pass C: clamped log(1-p) over ALL r (log2-domain), plus p at target.
    const float inv = 1.f / s;
    float sum_l2 = 0.f;
    float p_true = 0.f;
    #pragma unroll
    for (int k = 0; k < 19; ++k) {
        #pragma unroll
        for (int c = 0; c < 4; ++c) {
            const int r = k*4 + c;
            const float p  = (&x[k].x)[c] * inv;
            const float l2 = __log2f(1.f - p);
            sum_l2 += fmaxf(l2, NLN2F);
            if (r == true_r) p_true = p;
        }
    }
    float row_sum = LN2F * sum_l2;
    // Swap the true_r element's non-target term for the target term.
    const float l1c_t = fmaxf(LN2F * __log2f(1.f - p_true), -100.f);
    const float lp_t  = fmaxf(__logf(p_true), -100.f);   // p_true==0 (masked) -> -100
    row_sum += lp_t - l1c_t;

    // Block reduce -> one double partial per block (no atomics).
    #pragma unroll
    for (int off = 32; off; off >>= 1) row_sum += __shfl_xor(row_sum, off, 64);
    if ((tid & 63) == 0) sm_red[tid >> 6] = row_sum;
    __syncthreads();
    if (tid == 0)
        partials[blockIdx.x] = (double)((sm_red[0] + sm_red[1]) + (sm_red[2] + sm_red[3]));
}

// Sum NBCE bce partials + NMOM mom partials with the right scales.
__global__ __launch_bounds__(256) void final_kernel(
    const double* __restrict__ partials, float* __restrict__ out)
{
    __shared__ double sred[4];
    const int tid = threadIdx.x;
    double s = 0.0;
    for (int k = NMOM + tid; k < NBLK; k += 256) s += partials[k];
    double m = (tid < NMOM) ? partials[tid] : 0.0;
    double val = s * (-(double)SS / TOTAL_ELEMS) + m;
    #pragma unroll
    for (int off = 32; off; off >>= 1) val += __shfl_xor(val, off, 64);
    if ((tid & 63) == 0) sred[tid >> 6] = val;
    __syncthreads();
    if (tid == 0) out[0] = (float)((sred[0] + sred[1]) + (sred[2] + sred[3]));
}

extern "C" void kernel_launch(void* const* d_in, const int* in_sizes, int n_in,
                              void* d_out, int out_size, void* d_ws, size_t ws_size,
                              hipStream_t stream) {
    const float* model  = (const float*)d_in[0];   // [B,S,R]
    const float* mu     = (const float*)d_in[1];   // [B,Z]
    // d_in[2] = log_var — unused by the reference output
    const float* target = (const float*)d_in[3];   // [B,S,R] one-hot
    const float* masks  = (const float*)d_in[4];   // [NLHS,R]
    const int*   ind    = (const int*)  d_in[5];   // [R]
    float* out  = (float*)d_out;
    double* acc = (double*)d_ws;   // [0..NMOM) mom partials, [NMOM..NBLK) bce partials

    fused_kernel<<<NBLK, ROWS_PER_BLOCK, 0, stream>>>(model, target, masks, ind, mu, acc);
    final_kernel<<<1, 256, 0, stream>>>(acc, out);
}